// Round 6
// baseline (367.925 us; speedup 1.0000x reference)
//
#include <hip/hip_runtime.h>

#define N_NODES 50000
#define N_EDGES 1600000
#define HEADS 4
#define DPH 16
#define F_IN 128
#define HD 64   // HEADS * DPH

__device__ inline unsigned pack_bf16(float k, float v) {
    unsigned uk = __float_as_uint(k), uv = __float_as_uint(v);
    uk = (uk + 0x7FFFu + ((uk >> 16) & 1u)) >> 16;   // RNE to bf16
    uv = (uv + 0x7FFFu + ((uv >> 16) & 1u)) >> 16;
    return (uv << 16) | uk;
}

// ---------------------------------------------------------------------------
// Kernel 1: fused QKV projection (unchanged from round 5).
// KV[n*64 + h*16 + d] = bf16(v)<<16 | bf16(k).
// ---------------------------------------------------------------------------
__global__ void qkv_proj(const float* __restrict__ x,
                         const float* __restrict__ Wq,
                         const float* __restrict__ Wk,
                         const float* __restrict__ Wv,
                         float* __restrict__ Q,
                         unsigned* __restrict__ KV) {
    __shared__ float xs[8][F_IN];
    __shared__ float kcol[8][64];
    __shared__ float vcol[8][64];
    const int node0 = blockIdx.x * 8;
    const int tid = threadIdx.x;

    for (int i = tid; i < 8 * F_IN; i += 192) {
        const int n = node0 + (i >> 7);
        xs[i >> 7][i & 127] = (n < N_NODES) ? x[(long)n * F_IN + (i & 127)] : 0.f;
    }
    __syncthreads();

    const int m = tid / 64;       // 0=Q, 1=K, 2=V
    const int col = tid & 63;
    const float* W = (m == 0) ? Wq : (m == 1) ? Wk : Wv;

    float acc[8] = {0.f, 0.f, 0.f, 0.f, 0.f, 0.f, 0.f, 0.f};
    for (int k = 0; k < F_IN; k += 4) {
        const float w0 = W[(k + 0) * HD + col];
        const float w1 = W[(k + 1) * HD + col];
        const float w2 = W[(k + 2) * HD + col];
        const float w3 = W[(k + 3) * HD + col];
        #pragma unroll
        for (int i = 0; i < 8; ++i) {
            const float4 xv = *(const float4*)&xs[i][k];
            acc[i] += xv.x * w0 + xv.y * w1 + xv.z * w2 + xv.w * w3;
        }
    }

    if (m == 0) {
        #pragma unroll
        for (int i = 0; i < 8; ++i) {
            const int n = node0 + i;
            if (n < N_NODES) Q[n * HD + col] = acc[i];
        }
    } else if (m == 1) {
        #pragma unroll
        for (int i = 0; i < 8; ++i) kcol[i][col] = acc[i];
    } else {
        #pragma unroll
        for (int i = 0; i < 8; ++i) vcol[i][col] = acc[i];
    }
    __syncthreads();
    if (m == 1) {
        #pragma unroll
        for (int i = 0; i < 8; ++i) {
            const int n = node0 + i;
            if (n < N_NODES) KV[n * HD + col] = pack_bf16(kcol[i][col], vcol[i][col]);
        }
    }
}

// ---------------------------------------------------------------------------
// Kernel 2: linked list (single chain per node) + degree histogram.
// ---------------------------------------------------------------------------
__global__ void build_links(const int* __restrict__ src,
                            const int* __restrict__ dst,
                            int* __restrict__ head,
                            int* __restrict__ cnt,
                            int2* __restrict__ elink) {
    for (int i = blockIdx.x * blockDim.x + threadIdx.x; i < N_EDGES;
         i += gridDim.x * blockDim.x) {
        const int d = dst[i];
        atomicAdd(&cnt[d], 1);
        const int nx = atomicExch(&head[d], i);
        elink[i] = make_int2(src[i], nx);
    }
}

// ---------------------------------------------------------------------------
// Kernel 3: single-block exclusive scan of degrees -> off[0..N].
// ---------------------------------------------------------------------------
__global__ void scan_counts(const int* __restrict__ cnt, int* __restrict__ off) {
    __shared__ int wsum[16];
    __shared__ int carry_s;
    const int tid = threadIdx.x;
    const int lane = tid & 63;
    const int w = tid >> 6;
    if (tid == 0) carry_s = 0;
    __syncthreads();
    for (int base = 0; base < N_NODES; base += 1024) {
        const int i = base + tid;
        const int v = (i < N_NODES) ? cnt[i] : 0;
        int incl = v;
        #pragma unroll
        for (int s = 1; s < 64; s <<= 1) {
            const int t = __shfl_up(incl, s, 64);
            if (lane >= s) incl += t;
        }
        if (lane == 63) wsum[w] = incl;
        __syncthreads();
        if (w == 0) {
            int ws = (lane < 16) ? wsum[lane] : 0;
            #pragma unroll
            for (int s = 1; s < 16; s <<= 1) {
                const int t = __shfl_up(ws, s, 64);
                if (lane >= s) ws += t;
            }
            if (lane < 16) wsum[lane] = ws;
        }
        __syncthreads();
        const int c = carry_s;
        const int wbase = (w == 0) ? 0 : wsum[w - 1];
        const int excl = c + wbase + incl - v;
        if (i < N_NODES) off[i] = excl;
        __syncthreads();
        if (tid == 1023) carry_s = c + wsum[15];
        __syncthreads();
    }
    if (tid == 0) off[N_NODES] = carry_s;
}

// ---------------------------------------------------------------------------
// Kernel 4: CSR fill. One LANE per node walks its chain and writes srcs
// consecutively — each node's esrc region is written by exactly one wave
// (one XCD), so lines fill densely in one L2 (no cross-XCD write amp).
// ---------------------------------------------------------------------------
__global__ void csr_fill(const int* __restrict__ head,
                         const int2* __restrict__ elink,
                         const int* __restrict__ off,
                         int* __restrict__ esrc) {
    const int n = blockIdx.x * 64 + threadIdx.x;
    if (n >= N_NODES) return;
    int pos = off[n];
    int e = head[n];
    while (e >= 0) {
        const int2 l = elink[e];
        esrc[pos++] = l.x;
        e = l.y;
    }
}

// ---------------------------------------------------------------------------
// Kernel 5: CSR gather, one wave per node. lane = t*4 + h (t = edge slot
// 0..15, h = head). Fully lane-local hot loop: 4x uint4 KV load, 16-FMA dot,
// one exp, 16-FMA acc. No cross-lane ops until the per-node epilogue
// (reduce-scatter butterfly leaves lane (t,h) holding output dim t of head h).
// ---------------------------------------------------------------------------
__global__ void gather_csr(const int* __restrict__ off,
                           const int* __restrict__ esrc,
                           const float* __restrict__ Q,
                           const unsigned* __restrict__ KV,
                           float* __restrict__ out) {
    const int n = blockIdx.x * 4 + (threadIdx.x >> 6);
    if (n >= N_NODES) return;
    const int lane = threadIdx.x & 63;
    const int t = lane >> 2;
    const int h = lane & 3;
    const int beg = off[n];
    const int end = off[n + 1];

    float qv[16];
    {
        const float4* qp = (const float4*)(Q + (size_t)n * HD + h * DPH);
        #pragma unroll
        for (int j = 0; j < 4; ++j) {
            const float4 f = qp[j];
            qv[4 * j + 0] = f.x; qv[4 * j + 1] = f.y;
            qv[4 * j + 2] = f.z; qv[4 * j + 3] = f.w;
        }
    }

    float acc[16];
    #pragma unroll
    for (int j = 0; j < 16; ++j) acc[j] = 0.f;
    float zacc = 0.f;

    for (int base = beg; base < end; base += 16) {
        const int idx = base + t;
        const bool valid = idx < end;
        const int s = esrc[valid ? idx : end - 1];
        const uint4* kp = (const uint4*)(KV + (size_t)s * HD + h * DPH);
        const uint4 w0 = kp[0], w1 = kp[1], w2 = kp[2], w3 = kp[3];
        const unsigned kw[16] = {w0.x, w0.y, w0.z, w0.w,
                                 w1.x, w1.y, w1.z, w1.w,
                                 w2.x, w2.y, w2.z, w2.w,
                                 w3.x, w3.y, w3.z, w3.w};
        float p = 0.f;
        #pragma unroll
        for (int j = 0; j < 16; ++j)
            p = fmaf(__uint_as_float(kw[j] << 16), qv[j], p);
        p = fminf(fmaxf(p * 0.25f, -5.f), 5.f);
        float sc = __expf(p);
        sc = valid ? sc : 0.f;
        #pragma unroll
        for (int j = 0; j < 16; ++j)
            acc[j] = fmaf(sc, __uint_as_float(kw[j] & 0xFFFF0000u), acc[j]);
        zacc += sc;
    }

    // Reduce-scatter over t bits (masks 32,16,8,4 -> element bits 3,2,1,0).
    // After each step a lane keeps only elements matching its own t-bit.
    {
        const bool b = (lane & 32) != 0;
        float send[8], keep[8];
        #pragma unroll
        for (int j = 0; j < 8; ++j) {
            send[j] = b ? acc[j] : acc[j + 8];
            keep[j] = b ? acc[j + 8] : acc[j];
        }
        #pragma unroll
        for (int j = 0; j < 8; ++j) acc[j] = keep[j] + __shfl_xor(send[j], 32, 64);
    }
    {
        const bool b = (lane & 16) != 0;
        float send[4], keep[4];
        #pragma unroll
        for (int j = 0; j < 4; ++j) {
            send[j] = b ? acc[j] : acc[j + 4];
            keep[j] = b ? acc[j + 4] : acc[j];
        }
        #pragma unroll
        for (int j = 0; j < 4; ++j) acc[j] = keep[j] + __shfl_xor(send[j], 16, 64);
    }
    {
        const bool b = (lane & 8) != 0;
        float send[2], keep[2];
        #pragma unroll
        for (int j = 0; j < 2; ++j) {
            send[j] = b ? acc[j] : acc[j + 2];
            keep[j] = b ? acc[j + 2] : acc[j];
        }
        #pragma unroll
        for (int j = 0; j < 2; ++j) acc[j] = keep[j] + __shfl_xor(send[j], 8, 64);
    }
    {
        const bool b = (lane & 4) != 0;
        const float send = b ? acc[0] : acc[1];
        const float keep = b ? acc[1] : acc[0];
        acc[0] = keep + __shfl_xor(send, 4, 64);
    }

    // z: full butterfly over the 16 t-lanes (h bits untouched)
    zacc += __shfl_xor(zacc, 4, 64);
    zacc += __shfl_xor(zacc, 8, 64);
    zacc += __shfl_xor(zacc, 16, 64);
    zacc += __shfl_xor(zacc, 32, 64);

    out[(size_t)n * HD + h * DPH + t] = acc[0] / (zacc + 1e-6f);
}

extern "C" void kernel_launch(void* const* d_in, const int* in_sizes, int n_in,
                              void* d_out, int out_size, void* d_ws, size_t ws_size,
                              hipStream_t stream) {
    const float* x   = (const float*)d_in[0];
    const int*   src = (const int*)d_in[1];
    const int*   dst = (const int*)d_in[2];
    const float* Wq  = (const float*)d_in[3];
    const float* Wk  = (const float*)d_in[4];
    const float* Wv  = (const float*)d_in[5];
    float* out = (float*)d_out;

    float*    Q     = (float*)d_ws;                          // 3.2M f32
    unsigned* KV    = (unsigned*)(Q + (size_t)N_NODES * HD); // 3.2M u32
    int2*     elink = (int2*)(KV + (size_t)N_NODES * HD);    // E int2 (8B-aligned)
    int*      esrc  = (int*)(elink + (size_t)N_EDGES);       // E int
    int*      head  = esrc + N_EDGES;                        // N int
    int*      cnt   = head + N_NODES;                        // N int
    int*      off   = cnt + N_NODES;                         // N+1 int

    hipMemsetAsync(head, 0xFF, (size_t)N_NODES * sizeof(int), stream);
    hipMemsetAsync(cnt, 0, (size_t)N_NODES * sizeof(int), stream);

    qkv_proj<<<(N_NODES + 7) / 8, 192, 0, stream>>>(x, Wq, Wk, Wv, Q, KV);
    build_links<<<2048, 256, 0, stream>>>(src, dst, head, cnt, elink);
    scan_counts<<<1, 1024, 0, stream>>>(cnt, off);
    csr_fill<<<(N_NODES + 63) / 64, 64, 0, stream>>>(head, elink, off, esrc);
    gather_csr<<<(N_NODES + 3) / 4, 256, 0, stream>>>(off, esrc, Q, KV, out);
}

// Round 7
// 222.308 us; speedup vs baseline: 1.6550x; 1.6550x over previous
//
#include <hip/hip_runtime.h>

#define N_NODES 50000
#define N_EDGES 1600000
#define HEADS 4
#define DPH 16
#define F_IN 128
#define HD 64   // HEADS * DPH
#define NCHAIN 16

__device__ inline unsigned pack_bf16(float k, float v) {
    unsigned uk = __float_as_uint(k), uv = __float_as_uint(v);
    uk = (uk + 0x7FFFu + ((uk >> 16) & 1u)) >> 16;   // RNE to bf16
    uv = (uv + 0x7FFFu + ((uv >> 16) & 1u)) >> 16;
    return (uv << 16) | uk;
}

// ---------------------------------------------------------------------------
// Kernel 1: fused QKV projection (unchanged).
// KV[n*64 + h*16 + d] = bf16(v)<<16 | bf16(k).
// ---------------------------------------------------------------------------
__global__ void qkv_proj(const float* __restrict__ x,
                         const float* __restrict__ Wq,
                         const float* __restrict__ Wk,
                         const float* __restrict__ Wv,
                         float* __restrict__ Q,
                         unsigned* __restrict__ KV) {
    __shared__ float xs[8][F_IN];
    __shared__ float kcol[8][64];
    __shared__ float vcol[8][64];
    const int node0 = blockIdx.x * 8;
    const int tid = threadIdx.x;

    for (int i = tid; i < 8 * F_IN; i += 192) {
        const int n = node0 + (i >> 7);
        xs[i >> 7][i & 127] = (n < N_NODES) ? x[(long)n * F_IN + (i & 127)] : 0.f;
    }
    __syncthreads();

    const int m = tid / 64;       // 0=Q, 1=K, 2=V
    const int col = tid & 63;
    const float* W = (m == 0) ? Wq : (m == 1) ? Wk : Wv;

    float acc[8] = {0.f, 0.f, 0.f, 0.f, 0.f, 0.f, 0.f, 0.f};
    for (int k = 0; k < F_IN; k += 4) {
        const float w0 = W[(k + 0) * HD + col];
        const float w1 = W[(k + 1) * HD + col];
        const float w2 = W[(k + 2) * HD + col];
        const float w3 = W[(k + 3) * HD + col];
        #pragma unroll
        for (int i = 0; i < 8; ++i) {
            const float4 xv = *(const float4*)&xs[i][k];
            acc[i] += xv.x * w0 + xv.y * w1 + xv.z * w2 + xv.w * w3;
        }
    }

    if (m == 0) {
        #pragma unroll
        for (int i = 0; i < 8; ++i) {
            const int n = node0 + i;
            if (n < N_NODES) Q[n * HD + col] = acc[i];
        }
    } else if (m == 1) {
        #pragma unroll
        for (int i = 0; i < 8; ++i) kcol[i][col] = acc[i];
    } else {
        #pragma unroll
        for (int i = 0; i < 8; ++i) vcol[i][col] = acc[i];
    }
    __syncthreads();
    if (m == 1) {
        #pragma unroll
        for (int i = 0; i < 8; ++i) {
            const int n = node0 + i;
            if (n < N_NODES) KV[n * HD + col] = pack_bf16(kcol[i][col], vcol[i][col]);
        }
    }
}

// ---------------------------------------------------------------------------
// Kernel 2: 16 interleaved chains per dst node. ONE atomic per edge (the
// ~19G line-requests/s law makes this the grouping floor); elink write is
// fully coalesced. No histogram, no scan, no CSR fill.
// ---------------------------------------------------------------------------
__global__ void build_links(const int* __restrict__ src,
                            const int* __restrict__ dst,
                            int* __restrict__ head,
                            int2* __restrict__ elink) {
    for (int i = blockIdx.x * blockDim.x + threadIdx.x; i < N_EDGES;
         i += gridDim.x * blockDim.x) {
        const int d = dst[i];
        const int nx = atomicExch(&head[d * NCHAIN + (i & (NCHAIN - 1))], i);
        elink[i] = make_int2(src[i], nx);
    }
}

// ---------------------------------------------------------------------------
// Kernel 3: chain gather, one wave per node. lane = t*4 + h; the 4 h-lanes
// of slot t walk chain t together (elink load broadcasts across them, each
// loads its own 64B KV slice). Hot loop is fully lane-local: 4x uint4 load,
// 16-FMA dot, exp, 16-FMA acc. Avg chain length = deg/16 = 2 hops.
// ---------------------------------------------------------------------------
__global__ void gather_chains(const int* __restrict__ head,
                              const int2* __restrict__ elink,
                              const float* __restrict__ Q,
                              const unsigned* __restrict__ KV,
                              float* __restrict__ out) {
    const int n = blockIdx.x * 4 + (threadIdx.x >> 6);
    if (n >= N_NODES) return;
    const int lane = threadIdx.x & 63;
    const int t = lane >> 2;   // chain slot 0..15
    const int h = lane & 3;    // head

    float qv[16];
    {
        const float4* qp = (const float4*)(Q + (size_t)n * HD + h * DPH);
        #pragma unroll
        for (int j = 0; j < 4; ++j) {
            const float4 f = qp[j];
            qv[4 * j + 0] = f.x; qv[4 * j + 1] = f.y;
            qv[4 * j + 2] = f.z; qv[4 * j + 3] = f.w;
        }
    }

    float acc[16];
    #pragma unroll
    for (int j = 0; j < 16; ++j) acc[j] = 0.f;
    float zacc = 0.f;

    int e = head[n * NCHAIN + t];
    while (__ballot(e >= 0)) {
        if (e >= 0) {
            const int2 l = elink[e];
            const uint4* kp = (const uint4*)(KV + (size_t)l.x * HD + h * DPH);
            const uint4 w0 = kp[0], w1 = kp[1], w2 = kp[2], w3 = kp[3];
            const unsigned kw[16] = {w0.x, w0.y, w0.z, w0.w,
                                     w1.x, w1.y, w1.z, w1.w,
                                     w2.x, w2.y, w2.z, w2.w,
                                     w3.x, w3.y, w3.z, w3.w};
            float p = 0.f;
            #pragma unroll
            for (int j = 0; j < 16; ++j)
                p = fmaf(__uint_as_float(kw[j] << 16), qv[j], p);
            p = fminf(fmaxf(p * 0.25f, -5.f), 5.f);
            const float sc = __expf(p);
            #pragma unroll
            for (int j = 0; j < 16; ++j)
                acc[j] = fmaf(sc, __uint_as_float(kw[j] & 0xFFFF0000u), acc[j]);
            zacc += sc;
            e = l.y;
        }
    }

    // Reduce-scatter over t bits (masks 32,16,8,4 -> element bits 3,2,1,0).
    {
        const bool b = (lane & 32) != 0;
        float send[8], keep[8];
        #pragma unroll
        for (int j = 0; j < 8; ++j) {
            send[j] = b ? acc[j] : acc[j + 8];
            keep[j] = b ? acc[j + 8] : acc[j];
        }
        #pragma unroll
        for (int j = 0; j < 8; ++j) acc[j] = keep[j] + __shfl_xor(send[j], 32, 64);
    }
    {
        const bool b = (lane & 16) != 0;
        float send[4], keep[4];
        #pragma unroll
        for (int j = 0; j < 4; ++j) {
            send[j] = b ? acc[j] : acc[j + 4];
            keep[j] = b ? acc[j + 4] : acc[j];
        }
        #pragma unroll
        for (int j = 0; j < 4; ++j) acc[j] = keep[j] + __shfl_xor(send[j], 16, 64);
    }
    {
        const bool b = (lane & 8) != 0;
        float send[2], keep[2];
        #pragma unroll
        for (int j = 0; j < 2; ++j) {
            send[j] = b ? acc[j] : acc[j + 2];
            keep[j] = b ? acc[j + 2] : acc[j];
        }
        #pragma unroll
        for (int j = 0; j < 2; ++j) acc[j] = keep[j] + __shfl_xor(send[j], 8, 64);
    }
    {
        const bool b = (lane & 4) != 0;
        const float send = b ? acc[0] : acc[1];
        const float keep = b ? acc[1] : acc[0];
        acc[0] = keep + __shfl_xor(send, 4, 64);
    }

    // z: butterfly over the 16 t-lanes (h bits untouched)
    zacc += __shfl_xor(zacc, 4, 64);
    zacc += __shfl_xor(zacc, 8, 64);
    zacc += __shfl_xor(zacc, 16, 64);
    zacc += __shfl_xor(zacc, 32, 64);

    out[(size_t)n * HD + h * DPH + t] = acc[0] / (zacc + 1e-6f);
}

extern "C" void kernel_launch(void* const* d_in, const int* in_sizes, int n_in,
                              void* d_out, int out_size, void* d_ws, size_t ws_size,
                              hipStream_t stream) {
    const float* x   = (const float*)d_in[0];
    const int*   src = (const int*)d_in[1];
    const int*   dst = (const int*)d_in[2];
    const float* Wq  = (const float*)d_in[3];
    const float* Wk  = (const float*)d_in[4];
    const float* Wv  = (const float*)d_in[5];
    float* out = (float*)d_out;

    float*    Q     = (float*)d_ws;                          // 3.2M f32
    unsigned* KV    = (unsigned*)(Q + (size_t)N_NODES * HD); // 3.2M u32
    int2*     elink = (int2*)(KV + (size_t)N_NODES * HD);    // E int2
    int*      head  = (int*)(elink + (size_t)N_EDGES);       // N*16 int

    hipMemsetAsync(head, 0xFF, (size_t)N_NODES * NCHAIN * sizeof(int), stream);

    qkv_proj<<<(N_NODES + 7) / 8, 192, 0, stream>>>(x, Wq, Wk, Wv, Q, KV);
    build_links<<<2048, 256, 0, stream>>>(src, dst, head, elink);
    gather_chains<<<(N_NODES + 3) / 4, 256, 0, stream>>>(head, elink, Q, KV, out);
}

// Round 8
// 176.873 us; speedup vs baseline: 2.0802x; 1.2569x over previous
//
#include <hip/hip_runtime.h>

#define N_NODES 50000
#define N_EDGES 1600000
#define HEADS 4
#define DPH 16
#define F_IN 128
#define HD 64   // HEADS * DPH
#define NCHAIN 16

#define QKV_BLOCKS 6250            // ceil(N_NODES/8)
#define LINK_BLOCKS 2083           // blocks with (bx&3)==3 in [0,8333)
#define TOTAL_BLOCKS 8333

__device__ inline unsigned pack_bf16(float k, float v) {
    unsigned uk = __float_as_uint(k), uv = __float_as_uint(v);
    uk = (uk + 0x7FFFu + ((uk >> 16) & 1u)) >> 16;   // RNE to bf16
    uv = (uv + 0x7FFFu + ((uv >> 16) & 1u)) >> 16;
    return (uv << 16) | uk;
}

// ---------------------------------------------------------------------------
// Fat kernel: qkv projection blocks + link-build blocks in ONE launch.
// Roles interleaved (every 4th block builds links) so the VALU-bound qkv
// work and the atomic-unit-bound link build overlap from dispatch 0 —
// they use disjoint pipes (qkv: VALU+LDS, ~0 atomics; build: atomics, ~0
// VALU). Critical path becomes max(qkv, build) instead of qkv + build.
// ---------------------------------------------------------------------------
__global__ void __launch_bounds__(256)
qkv_and_links(const float* __restrict__ x,
              const float* __restrict__ Wq,
              const float* __restrict__ Wk,
              const float* __restrict__ Wv,
              const int* __restrict__ src,
              const int* __restrict__ dst,
              float* __restrict__ Q,
              unsigned* __restrict__ KV,
              int* __restrict__ head,
              int2* __restrict__ elink) {
    const int bx = blockIdx.x;
    const int tid = threadIdx.x;

    if ((bx & 3) == 3) {
        // ---- link-build role: 16 interleaved chains per dst node ----
        const int bid = bx >> 2;   // 0 .. LINK_BLOCKS-1
        for (int i = bid * 256 + tid; i < N_EDGES; i += LINK_BLOCKS * 256) {
            const int d = dst[i];
            const int nx = atomicExch(&head[d * NCHAIN + (i & (NCHAIN - 1))], i);
            elink[i] = make_int2(src[i], nx);
        }
        return;
    }

    // ---- qkv role ----
    const int qb = bx - (bx >> 2);   // dense qkv block id (build slots removed)
    if (qb >= QKV_BLOCKS) return;

    __shared__ float xs[8][F_IN];
    __shared__ float kcol[8][64];
    __shared__ float vcol[8][64];
    const int node0 = qb * 8;

    for (int i = tid; i < 8 * F_IN; i += 256) {
        const int n = node0 + (i >> 7);
        xs[i >> 7][i & 127] = (n < N_NODES) ? x[(long)n * F_IN + (i & 127)] : 0.f;
    }
    __syncthreads();

    const int m = tid >> 6;       // 0=Q, 1=K, 2=V, 3=idle
    const int col = tid & 63;

    if (m < 3) {
        const float* W = (m == 0) ? Wq : (m == 1) ? Wk : Wv;
        float acc[8] = {0.f, 0.f, 0.f, 0.f, 0.f, 0.f, 0.f, 0.f};
        for (int k = 0; k < F_IN; k += 4) {
            const float w0 = W[(k + 0) * HD + col];
            const float w1 = W[(k + 1) * HD + col];
            const float w2 = W[(k + 2) * HD + col];
            const float w3 = W[(k + 3) * HD + col];
            #pragma unroll
            for (int i = 0; i < 8; ++i) {
                const float4 xv = *(const float4*)&xs[i][k];
                acc[i] += xv.x * w0 + xv.y * w1 + xv.z * w2 + xv.w * w3;
            }
        }
        if (m == 0) {
            #pragma unroll
            for (int i = 0; i < 8; ++i) {
                const int n = node0 + i;
                if (n < N_NODES) Q[n * HD + col] = acc[i];
            }
        } else if (m == 1) {
            #pragma unroll
            for (int i = 0; i < 8; ++i) kcol[i][col] = acc[i];
        } else {
            #pragma unroll
            for (int i = 0; i < 8; ++i) vcol[i][col] = acc[i];
        }
    }
    __syncthreads();
    if (m == 1) {
        #pragma unroll
        for (int i = 0; i < 8; ++i) {
            const int n = node0 + i;
            if (n < N_NODES) KV[n * HD + col] = pack_bf16(kcol[i][col], vcol[i][col]);
        }
    }
}

// ---------------------------------------------------------------------------
// Gather: one wave per node. lane = t*4 + h; the 4 h-lanes of chain-slot t
// walk chain t together (elink load broadcasts across them, each loads its
// own 64B KV slice). Hot loop fully lane-local: 4x uint4 load, 16-FMA dot,
// exp, 16-FMA acc. Epilogue: reduce-scatter butterfly over t bits.
// ---------------------------------------------------------------------------
__global__ void gather_chains(const int* __restrict__ head,
                              const int2* __restrict__ elink,
                              const float* __restrict__ Q,
                              const unsigned* __restrict__ KV,
                              float* __restrict__ out) {
    const int n = blockIdx.x * 4 + (threadIdx.x >> 6);
    if (n >= N_NODES) return;
    const int lane = threadIdx.x & 63;
    const int t = lane >> 2;   // chain slot 0..15
    const int h = lane & 3;    // head

    float qv[16];
    {
        const float4* qp = (const float4*)(Q + (size_t)n * HD + h * DPH);
        #pragma unroll
        for (int j = 0; j < 4; ++j) {
            const float4 f = qp[j];
            qv[4 * j + 0] = f.x; qv[4 * j + 1] = f.y;
            qv[4 * j + 2] = f.z; qv[4 * j + 3] = f.w;
        }
    }

    float acc[16];
    #pragma unroll
    for (int j = 0; j < 16; ++j) acc[j] = 0.f;
    float zacc = 0.f;

    int e = head[n * NCHAIN + t];
    while (__ballot(e >= 0)) {
        if (e >= 0) {
            const int2 l = elink[e];
            const uint4* kp = (const uint4*)(KV + (size_t)l.x * HD + h * DPH);
            const uint4 w0 = kp[0], w1 = kp[1], w2 = kp[2], w3 = kp[3];
            const unsigned kw[16] = {w0.x, w0.y, w0.z, w0.w,
                                     w1.x, w1.y, w1.z, w1.w,
                                     w2.x, w2.y, w2.z, w2.w,
                                     w3.x, w3.y, w3.z, w3.w};
            float p = 0.f;
            #pragma unroll
            for (int j = 0; j < 16; ++j)
                p = fmaf(__uint_as_float(kw[j] << 16), qv[j], p);
            p = fminf(fmaxf(p * 0.25f, -5.f), 5.f);
            const float sc = __expf(p);
            #pragma unroll
            for (int j = 0; j < 16; ++j)
                acc[j] = fmaf(sc, __uint_as_float(kw[j] & 0xFFFF0000u), acc[j]);
            zacc += sc;
            e = l.y;
        }
    }

    // Reduce-scatter over t bits (masks 32,16,8,4 -> element bits 3,2,1,0).
    {
        const bool b = (lane & 32) != 0;
        float send[8], keep[8];
        #pragma unroll
        for (int j = 0; j < 8; ++j) {
            send[j] = b ? acc[j] : acc[j + 8];
            keep[j] = b ? acc[j + 8] : acc[j];
        }
        #pragma unroll
        for (int j = 0; j < 8; ++j) acc[j] = keep[j] + __shfl_xor(send[j], 32, 64);
    }
    {
        const bool b = (lane & 16) != 0;
        float send[4], keep[4];
        #pragma unroll
        for (int j = 0; j < 4; ++j) {
            send[j] = b ? acc[j] : acc[j + 4];
            keep[j] = b ? acc[j + 4] : acc[j];
        }
        #pragma unroll
        for (int j = 0; j < 4; ++j) acc[j] = keep[j] + __shfl_xor(send[j], 16, 64);
    }
    {
        const bool b = (lane & 8) != 0;
        float send[2], keep[2];
        #pragma unroll
        for (int j = 0; j < 2; ++j) {
            send[j] = b ? acc[j] : acc[j + 2];
            keep[j] = b ? acc[j + 2] : acc[j];
        }
        #pragma unroll
        for (int j = 0; j < 2; ++j) acc[j] = keep[j] + __shfl_xor(send[j], 8, 64);
    }
    {
        const bool b = (lane & 4) != 0;
        const float send = b ? acc[0] : acc[1];
        const float keep = b ? acc[1] : acc[0];
        acc[0] = keep + __shfl_xor(send, 4, 64);
    }

    // z: butterfly over the 16 t-lanes (h bits untouched)
    zacc += __shfl_xor(zacc, 4, 64);
    zacc += __shfl_xor(zacc, 8, 64);
    zacc += __shfl_xor(zacc, 16, 64);
    zacc += __shfl_xor(zacc, 32, 64);

    out[(size_t)n * HD + h * DPH + t] = acc[0] / (zacc + 1e-6f);
}

extern "C" void kernel_launch(void* const* d_in, const int* in_sizes, int n_in,
                              void* d_out, int out_size, void* d_ws, size_t ws_size,
                              hipStream_t stream) {
    const float* x   = (const float*)d_in[0];
    const int*   src = (const int*)d_in[1];
    const int*   dst = (const int*)d_in[2];
    const float* Wq  = (const float*)d_in[3];
    const float* Wk  = (const float*)d_in[4];
    const float* Wv  = (const float*)d_in[5];
    float* out = (float*)d_out;

    float*    Q     = (float*)d_ws;                          // 3.2M f32
    unsigned* KV    = (unsigned*)(Q + (size_t)N_NODES * HD); // 3.2M u32
    int2*     elink = (int2*)(KV + (size_t)N_NODES * HD);    // E int2
    int*      head  = (int*)(elink + (size_t)N_EDGES);       // N*16 int

    hipMemsetAsync(head, 0xFF, (size_t)N_NODES * NCHAIN * sizeof(int), stream);

    qkv_and_links<<<TOTAL_BLOCKS, 256, 0, stream>>>(x, Wq, Wk, Wv, src, dst,
                                                    Q, KV, head, elink);
    gather_chains<<<(N_NODES + 3) / 4, 256, 0, stream>>>(head, elink, Q, KV, out);
}

// Round 9
// 159.415 us; speedup vs baseline: 2.3080x; 1.1095x over previous
//
#include <hip/hip_runtime.h>

#define N_NODES 50000
#define N_EDGES 1600000
#define HEADS 4
#define DPH 16
#define F_IN 128
#define HD 64   // HEADS * DPH
#define NCHAIN 16

#define QKV_BLOCKS 3125            // 50000 / 16, exact
#define LINK_BLOCKS 1041           // blocks with (bx&3)==3 in [0,4166)
#define TOTAL_BLOCKS 4166          // 3125 qkv + 1041 link

__device__ inline unsigned pack_bf16(float k, float v) {
    unsigned uk = __float_as_uint(k), uv = __float_as_uint(v);
    uk = (uk + 0x7FFFu + ((uk >> 16) & 1u)) >> 16;   // RNE to bf16
    uv = (uv + 0x7FFFu + ((uv >> 16) & 1u)) >> 16;
    return (uv << 16) | uk;
}

// ---------------------------------------------------------------------------
// Fat kernel: qkv projection + link build, interleaved block roles.
// qkv role: 16 nodes/block, 2-D register tiling — each compute lane owns a
// 4-node x 4-col acc tile, so one 4-k step is 8 b128 reads for 64 FMAs
// (round-7 structure needed 12 reads per 32 FMAs and 2x the L2 W-traffic).
// link role: 16 interleaved chains/node, ONE atomicExch per edge (the ~19G
// line-req/s memory-side atomic law makes that the grouping floor).
// ---------------------------------------------------------------------------
__global__ void __launch_bounds__(256)
qkv_and_links(const float* __restrict__ x,
              const float* __restrict__ Wq,
              const float* __restrict__ Wk,
              const float* __restrict__ Wv,
              const int* __restrict__ src,
              const int* __restrict__ dst,
              float* __restrict__ Q,
              unsigned* __restrict__ KV,
              int* __restrict__ head,
              int2* __restrict__ elink) {
    const int bx = blockIdx.x;
    const int tid = threadIdx.x;

    if ((bx & 3) == 3) {
        // ---- link-build role ----
        const int bid = bx >> 2;   // 0 .. LINK_BLOCKS-1
        for (int i = bid * 256 + tid; i < N_EDGES; i += LINK_BLOCKS * 256) {
            const int d = dst[i];
            const int nx = atomicExch(&head[d * NCHAIN + (i & (NCHAIN - 1))], i);
            elink[i] = make_int2(src[i], nx);
        }
        return;
    }

    // ---- qkv role ----
    const int qb = bx - (bx >> 2);   // dense qkv block id (link slots removed)
    // qb < QKV_BLOCKS for all bx < TOTAL_BLOCKS by construction.

    __shared__ float xs[16][F_IN + 4];   // +4 pad: node-groups land 2-way (free)
    __shared__ float kcol[16][68];
    __shared__ float vcol[16][68];
    const int node0 = qb * 16;

    // stage 16 node rows (row-aware so the pad is preserved)
    for (int i = tid; i < 512; i += 256) {           // 512 float4 = 16 x 32
        const int r = i >> 5, c4 = (i & 31) * 4;
        *(float4*)&xs[r][c4] = *(const float4*)&x[(size_t)(node0 + r) * F_IN + c4];
    }
    __syncthreads();

    const int m = tid >> 6;          // 0=Q, 1=K, 2=V, 3=pack-helper
    const int lane = tid & 63;
    const int cg = (lane & 15) * 4;  // col base (16 groups x 4 cols = 64)
    const int ng = (lane >> 4) * 4;  // node base (4 groups x 4 nodes = 16)

    if (m < 3) {
        const float* W = (m == 0) ? Wq : (m == 1) ? Wk : Wv;
        float acc[4][4];
        #pragma unroll
        for (int i = 0; i < 4; ++i)
            #pragma unroll
            for (int j = 0; j < 4; ++j) acc[i][j] = 0.f;

        for (int k = 0; k < F_IN; k += 4) {
            const float4 xv0 = *(const float4*)&xs[ng + 0][k];
            const float4 xv1 = *(const float4*)&xs[ng + 1][k];
            const float4 xv2 = *(const float4*)&xs[ng + 2][k];
            const float4 xv3 = *(const float4*)&xs[ng + 3][k];
            const float4 w0 = *(const float4*)&W[(k + 0) * HD + cg];
            const float4 w1 = *(const float4*)&W[(k + 1) * HD + cg];
            const float4 w2 = *(const float4*)&W[(k + 2) * HD + cg];
            const float4 w3 = *(const float4*)&W[(k + 3) * HD + cg];
            #pragma unroll
            for (int i = 0; i < 4; ++i) {
                const float4 xv = (i == 0) ? xv0 : (i == 1) ? xv1 : (i == 2) ? xv2 : xv3;
                acc[i][0] += xv.x * w0.x + xv.y * w1.x + xv.z * w2.x + xv.w * w3.x;
                acc[i][1] += xv.x * w0.y + xv.y * w1.y + xv.z * w2.y + xv.w * w3.y;
                acc[i][2] += xv.x * w0.z + xv.y * w1.z + xv.z * w2.z + xv.w * w3.z;
                acc[i][3] += xv.x * w0.w + xv.y * w1.w + xv.z * w2.w + xv.w * w3.w;
            }
        }

        if (m == 0) {
            #pragma unroll
            for (int i = 0; i < 4; ++i)
                *(float4*)&Q[(size_t)(node0 + ng + i) * HD + cg] =
                    make_float4(acc[i][0], acc[i][1], acc[i][2], acc[i][3]);
        } else if (m == 1) {
            #pragma unroll
            for (int i = 0; i < 4; ++i)
                *(float4*)&kcol[ng + i][cg] =
                    make_float4(acc[i][0], acc[i][1], acc[i][2], acc[i][3]);
        } else {
            #pragma unroll
            for (int i = 0; i < 4; ++i)
                *(float4*)&vcol[ng + i][cg] =
                    make_float4(acc[i][0], acc[i][1], acc[i][2], acc[i][3]);
        }
    }
    __syncthreads();

    // pack K,V -> interleaved bf16 (all 256 threads, 4 entries each)
    for (int i = tid; i < 16 * 64; i += 256) {
        const int nn = i >> 6, cc = i & 63;
        KV[(size_t)(node0 + nn) * HD + cc] = pack_bf16(kcol[nn][cc], vcol[nn][cc]);
    }
}

// ---------------------------------------------------------------------------
// Gather: one wave per node. lane = t*4 + h; the 4 h-lanes of chain-slot t
// walk chain t together (elink load broadcasts, each h-lane loads its own
// 64B KV slice). Hot loop fully lane-local; epilogue reduce-scatter.
// ---------------------------------------------------------------------------
__global__ void gather_chains(const int* __restrict__ head,
                              const int2* __restrict__ elink,
                              const float* __restrict__ Q,
                              const unsigned* __restrict__ KV,
                              float* __restrict__ out) {
    const int n = blockIdx.x * 4 + (threadIdx.x >> 6);
    if (n >= N_NODES) return;
    const int lane = threadIdx.x & 63;
    const int t = lane >> 2;   // chain slot 0..15
    const int h = lane & 3;    // head

    float qv[16];
    {
        const float4* qp = (const float4*)(Q + (size_t)n * HD + h * DPH);
        #pragma unroll
        for (int j = 0; j < 4; ++j) {
            const float4 f = qp[j];
            qv[4 * j + 0] = f.x; qv[4 * j + 1] = f.y;
            qv[4 * j + 2] = f.z; qv[4 * j + 3] = f.w;
        }
    }

    float acc[16];
    #pragma unroll
    for (int j = 0; j < 16; ++j) acc[j] = 0.f;
    float zacc = 0.f;

    int e = head[n * NCHAIN + t];
    while (__ballot(e >= 0)) {
        if (e >= 0) {
            const int2 l = elink[e];
            const uint4* kp = (const uint4*)(KV + (size_t)l.x * HD + h * DPH);
            const uint4 w0 = kp[0], w1 = kp[1], w2 = kp[2], w3 = kp[3];
            const unsigned kw[16] = {w0.x, w0.y, w0.z, w0.w,
                                     w1.x, w1.y, w1.z, w1.w,
                                     w2.x, w2.y, w2.z, w2.w,
                                     w3.x, w3.y, w3.z, w3.w};
            float p = 0.f;
            #pragma unroll
            for (int j = 0; j < 16; ++j)
                p = fmaf(__uint_as_float(kw[j] << 16), qv[j], p);
            p = fminf(fmaxf(p * 0.25f, -5.f), 5.f);
            const float sc = __expf(p);
            #pragma unroll
            for (int j = 0; j < 16; ++j)
                acc[j] = fmaf(sc, __uint_as_float(kw[j] & 0xFFFF0000u), acc[j]);
            zacc += sc;
            e = l.y;
        }
    }

    // Reduce-scatter over t bits (masks 32,16,8,4 -> element bits 3,2,1,0).
    {
        const bool b = (lane & 32) != 0;
        float send[8], keep[8];
        #pragma unroll
        for (int j = 0; j < 8; ++j) {
            send[j] = b ? acc[j] : acc[j + 8];
            keep[j] = b ? acc[j + 8] : acc[j];
        }
        #pragma unroll
        for (int j = 0; j < 8; ++j) acc[j] = keep[j] + __shfl_xor(send[j], 32, 64);
    }
    {
        const bool b = (lane & 16) != 0;
        float send[4], keep[4];
        #pragma unroll
        for (int j = 0; j < 4; ++j) {
            send[j] = b ? acc[j] : acc[j + 4];
            keep[j] = b ? acc[j + 4] : acc[j];
        }
        #pragma unroll
        for (int j = 0; j < 4; ++j) acc[j] = keep[j] + __shfl_xor(send[j], 16, 64);
    }
    {
        const bool b = (lane & 8) != 0;
        float send[2], keep[2];
        #pragma unroll
        for (int j = 0; j < 2; ++j) {
            send[j] = b ? acc[j] : acc[j + 2];
            keep[j] = b ? acc[j + 2] : acc[j];
        }
        #pragma unroll
        for (int j = 0; j < 2; ++j) acc[j] = keep[j] + __shfl_xor(send[j], 8, 64);
    }
    {
        const bool b = (lane & 4) != 0;
        const float send = b ? acc[0] : acc[1];
        const float keep = b ? acc[1] : acc[0];
        acc[0] = keep + __shfl_xor(send, 4, 64);
    }

    // z: butterfly over the 16 t-lanes (h bits untouched)
    zacc += __shfl_xor(zacc, 4, 64);
    zacc += __shfl_xor(zacc, 8, 64);
    zacc += __shfl_xor(zacc, 16, 64);
    zacc += __shfl_xor(zacc, 32, 64);

    out[(size_t)n * HD + h * DPH + t] = acc[0] / (zacc + 1e-6f);
}

extern "C" void kernel_launch(void* const* d_in, const int* in_sizes, int n_in,
                              void* d_out, int out_size, void* d_ws, size_t ws_size,
                              hipStream_t stream) {
    const float* x   = (const float*)d_in[0];
    const int*   src = (const int*)d_in[1];
    const int*   dst = (const int*)d_in[2];
    const float* Wq  = (const float*)d_in[3];
    const float* Wk  = (const float*)d_in[4];
    const float* Wv  = (const float*)d_in[5];
    float* out = (float*)d_out;

    float*    Q     = (float*)d_ws;                          // 3.2M f32
    unsigned* KV    = (unsigned*)(Q + (size_t)N_NODES * HD); // 3.2M u32
    int2*     elink = (int2*)(KV + (size_t)N_NODES * HD);    // E int2
    int*      head  = (int*)(elink + (size_t)N_EDGES);       // N*16 int

    hipMemsetAsync(head, 0xFF, (size_t)N_NODES * NCHAIN * sizeof(int), stream);

    qkv_and_links<<<TOTAL_BLOCKS, 256, 0, stream>>>(x, Wq, Wk, Wv, src, dst,
                                                    Q, KV, head, elink);
    gather_chains<<<(N_NODES + 3) / 4, 256, 0, stream>>>(head, elink, Q, KV, out);
}